// Round 7
// baseline (214.266 us; speedup 1.0000x reference)
//
#include <hip/hip_runtime.h>
#include <hip/hip_bf16.h>

#define B_  2
#define T_  2048
#define C_  768
#define H_  12
#define HD_ 64

// scores are computed in exp2 domain: Q is pre-scaled by 0.125*log2(e)
#define QSCALE 0.18033688011f
#define DTHR   11.5415603f   /* 8*log2(e) */

typedef short bf16x8 __attribute__((ext_vector_type(8)));
typedef float f32x4  __attribute__((ext_vector_type(4)));
typedef unsigned short u16;

__device__ __forceinline__ u16 f2b(float f) {
  __hip_bfloat16 h = __float2bfloat16(f);
  return __builtin_bit_cast(u16, h);
}

__device__ __forceinline__ void gload_lds16(const u16* g, u16* l) {
  __builtin_amdgcn_global_load_lds(
      (__attribute__((address_space(1))) void*)(void*)g,
      (__attribute__((address_space(3))) void*)(void*)l,
      16, 0, 0);
}

// ---------------- LayerNorm: fp32 in -> bf16 out ----------------
__global__ __launch_bounds__(256) void ln_kernel(const float* __restrict__ x,
                                                 const float* __restrict__ g,
                                                 const float* __restrict__ b,
                                                 u16* __restrict__ out) {
  int row = blockIdx.x;
  int tid = threadIdx.x;
  const float* xr = x + (size_t)row * C_;
  float v0 = xr[tid], v1 = xr[tid + 256], v2 = xr[tid + 512];
  float s = v0 + v1 + v2;
  float q = v0 * v0 + v1 * v1 + v2 * v2;
  for (int m = 1; m < 64; m <<= 1) {
    s += __shfl_xor(s, m, 64);
    q += __shfl_xor(q, m, 64);
  }
  __shared__ float red[8];
  int wv = tid >> 6, ln = tid & 63;
  if (ln == 0) { red[wv] = s; red[4 + wv] = q; }
  __syncthreads();
  s = red[0] + red[1] + red[2] + red[3];
  q = red[4] + red[5] + red[6] + red[7];
  float mu  = s * (1.0f / C_);
  float var = q * (1.0f / C_) - mu * mu;
  float rs  = rsqrtf(var + 1e-5f);
  u16* orow = out + (size_t)row * C_;
  orow[tid]       = f2b(g[tid]       * (v0 - mu) * rs + b[tid]);
  orow[tid + 256] = f2b(g[tid + 256] * (v1 - mu) * rs + b[tid + 256]);
  orow[tid + 512] = f2b(g[tid + 512] * (v2 - mu) * rs + b[tid + 512]);
}

// ------------- transpose+convert: fp32 W[K,N] -> bf16 Bt[N,K] -------------
__device__ __forceinline__ void tcvt_body(const float* __restrict__ W,
                                          u16* __restrict__ Bt,
                                          int Kd, int Nd, int bx, int by) {
  __shared__ u16 tile[32][33];
  int j0 = bx * 32, i0 = by * 32;
  int tx = threadIdx.x & 31, ty = threadIdx.x >> 5;  // ty 0..7
#pragma unroll
  for (int p = 0; p < 4; p++)
    tile[p * 8 + ty][tx] = f2b(W[(size_t)(i0 + p * 8 + ty) * Nd + j0 + tx]);
  __syncthreads();
#pragma unroll
  for (int p = 0; p < 4; p++)
    Bt[(size_t)(j0 + p * 8 + ty) * Kd + i0 + tx] = tile[tx][p * 8 + ty];
}

__global__ __launch_bounds__(256) void tcvt_kernel(const float* __restrict__ W,
                                                   u16* __restrict__ Bt,
                                                   int Kd, int Nd) {
  tcvt_body(W, Bt, Kd, Nd, blockIdx.x, blockIdx.y);
}

// four 768x768 transposes in one launch (z selects the weight)
__global__ __launch_bounds__(256) void tcvt4_kernel(const float* __restrict__ W0,
                                                    const float* __restrict__ W1,
                                                    const float* __restrict__ W2,
                                                    const float* __restrict__ W3,
                                                    u16* __restrict__ O0,
                                                    u16* __restrict__ O1,
                                                    u16* __restrict__ O2,
                                                    u16* __restrict__ O3) {
  const float* W = (blockIdx.z == 0) ? W0 : (blockIdx.z == 1) ? W1
                  : (blockIdx.z == 2) ? W2 : W3;
  u16* O = (blockIdx.z == 0) ? O0 : (blockIdx.z == 1) ? O1
          : (blockIdx.z == 2) ? O2 : O3;
  tcvt_body(W, O, 768, 768, blockIdx.x, blockIdx.y);
}

// ------------- GEMM: C[M,N] = A[M,K](bf16) * Bt[N,K]^T(bf16) -------------
// 128x64 tile, BK=64, triple-buffered LDS, 2-deep prefetch with counted
// vmcnt (T4): loads stay in flight across the raw s_barrier; stage(t) is
// awaited two compute phases after issue. 6 gload_lds/thread per stage.
// XOR-swizzled LDS (inverse-swizzled global source, swizzled reads).
// MODE 1: fused QKV epilogue (q pre-scaled, [B,H,T,64]; k same; v^T [B,H,64,T])
// MODE 3/5: fp32 acc+bias+resid   4: bf16 gelu(acc+bias)
template <int MODE>
__global__ __launch_bounds__(256) void gemm_p(const u16* __restrict__ A,
                                              const u16* __restrict__ Bt,
                                              int K, int N,
                                              u16* __restrict__ outB,
                                              float* __restrict__ outF,
                                              const float* __restrict__ bias,
                                              const float* __restrict__ resid) {
  constexpr int NR = 2;            // 16-col fragments per wave
  constexpr int BN = NR * 32;      // 64
  __shared__ u16 As[3][128 * 64];
  __shared__ u16 Bs[3][BN * 64];
  int tid = threadIdx.x;
  int wave = tid >> 6, lane = tid & 63;
  int wr = wave >> 1, wc = wave & 1;
  int laneQ = lane >> 4, laneM = lane & 15;
  int bm = blockIdx.x * 128, bn = blockIdx.y * BN;

  f32x4 zero = {0.f, 0.f, 0.f, 0.f};
  f32x4 acc[4][NR];
#pragma unroll
  for (int m = 0; m < 4; m++)
#pragma unroll
    for (int n = 0; n < NR; n++) acc[m][n] = zero;

  auto stage = [&](int buf, int k0) {
#pragma unroll
    for (int i = 0; i < 4; i++) {
      int c = i * 256 + tid;
      int row = c >> 3, sw = (c & 7) ^ (row & 7);
      gload_lds16(A + (size_t)(bm + row) * K + k0 + (sw << 3),
                  &As[buf][(size_t)(i * 256 + wave * 64) * 8]);
    }
#pragma unroll
    for (int i = 0; i < NR; i++) {
      int c = i * 256 + tid;
      int row = c >> 3, sw = (c & 7) ^ (row & 7);
      gload_lds16(Bt + (size_t)(bn + row) * K + k0 + (sw << 3),
                  &Bs[buf][(size_t)(i * 256 + wave * 64) * 8]);
    }
  };

  auto compute = [&](int buf) {
    const u16* Ab = As[buf];
    const u16* Bb = Bs[buf];
#pragma unroll
    for (int kk = 0; kk < 2; kk++) {
      bf16x8 af[4], bfr[NR];
#pragma unroll
      for (int m = 0; m < 4; m++) {
        int row = wr * 64 + m * 16 + laneM;
        af[m] = *(const bf16x8*)(Ab + row * 64 +
                                 ((((kk << 2) | laneQ) ^ (row & 7)) << 3));
      }
#pragma unroll
      for (int n = 0; n < NR; n++) {
        int row = wc * (NR * 16) + n * 16 + laneM;
        bfr[n] = *(const bf16x8*)(Bb + row * 64 +
                                  ((((kk << 2) | laneQ) ^ (row & 7)) << 3));
      }
#pragma unroll
      for (int m = 0; m < 4; m++)
#pragma unroll
        for (int n = 0; n < NR; n++)
          acc[m][n] = __builtin_amdgcn_mfma_f32_16x16x32_bf16(af[m], bfr[n],
                                                              acc[m][n], 0, 0, 0);
    }
  };

  int nk = K >> 6;                 // >= 12 for all our shapes
  stage(0, 0);
  stage(1, 64);
  for (int t = 0; t < nk; ++t) {
    int cur = t % 3;
    // wait for stage(t) only: stage(t+1) (6 loads) may stay in flight
    if (t < nk - 1) asm volatile("s_waitcnt vmcnt(6)" ::: "memory");
    else            asm volatile("s_waitcnt vmcnt(0)" ::: "memory");
    __builtin_amdgcn_s_barrier();
    __builtin_amdgcn_sched_barrier(0);
    if (t + 2 < nk) stage((t + 2) % 3, (t + 2) << 6);
    compute(cur);
  }

  u16* kout  = outB + (size_t)4096 * 768;
  u16* vtout = outB + (size_t)2 * 4096 * 768;
#pragma unroll
  for (int m = 0; m < 4; m++) {
#pragma unroll
    for (int n = 0; n < NR; n++) {
#pragma unroll
      for (int r = 0; r < 4; r++) {
        int row = bm + wr * 64 + m * 16 + laneQ * 4 + r;
        int col = bn + wc * NR * 16 + n * 16 + laneM;
        float v = acc[m][n][r];
        if (MODE == 1) {
          int b = row >> 11, t = row & 2047;
          int which = col / 768;
          int cc = col - which * 768;
          int h = cc >> 6, d = cc & 63;
          if (which == 0)
            outB[(((size_t)(b * H_ + h)) * T_ + t) * HD_ + d] = f2b(v * QSCALE);
          else if (which == 1)
            kout[(((size_t)(b * H_ + h)) * T_ + t) * HD_ + d] = f2b(v);
          else
            vtout[(((size_t)(b * H_ + h)) * HD_ + d) * T_ + t] = f2b(v);
        } else if (MODE == 3 || MODE == 5) {
          outF[(size_t)row * N + col] = v + bias[col] + resid[(size_t)row * N + col];
        } else if (MODE == 4) {
          float u = v + bias[col];
          outB[(size_t)row * N + col] = f2b(0.5f * u * (1.0f + erff(u * 0.70710678118f)));
        }
      }
    }
  }
}

// ------------- flash attention, LDS-staged K/V, KVBLK=64 -------------
// Q (pre-scaled by 0.125*log2e), K: [B*H, T, 64] bf16. Vt: [B*H, 64, T] bf16.
// ctx out: [B, T, C] bf16. 4 waves x 16 q-rows; LDS exactly 40960B ->
// 4 blocks/CU. Snake-balanced 768-block LPT grid.
__global__ __launch_bounds__(256) void attn_kernel(const u16* __restrict__ Q,
                                                   const u16* __restrict__ K,
                                                   const u16* __restrict__ Vt,
                                                   u16* __restrict__ ctx) {
  __shared__ u16 Ks[2][4096];
  __shared__ u16 Vs[2][4096];
  __shared__ u16 p_lds[4][1024];   // [16 rows][64 cols], XOR-swizzled

  int tid = threadIdx.x;
  int wave = tid >> 6, lane = tid & 63;
  int laneQ = lane >> 4, laneM = lane & 15;
  int id = blockIdx.x;
  int pass = id >> 8, slot = id & 255;
  int ii = pass * 256 + ((pass == 1) ? 255 - slot : slot);  // snake balance
  int bh = ii % 24;
  int bx = 31 - ii / 24;   // LPT: longest first
  int q0 = bx * 64 + wave * 16;

  const u16* Qb = Q  + ((size_t)bh * T_ + q0) * HD_;
  const u16* Kb = K  + (size_t)bh * T_ * HD_;
  const u16* Vb = Vt + (size_t)bh * HD_ * T_;

  bf16x8 qf[2];
  qf[0] = *(const bf16x8*)(Qb + laneM * HD_ + laneQ * 8);
  qf[1] = *(const bf16x8*)(Qb + laneM * HD_ + 32 + laneQ * 8);

  f32x4 zero = {0.f, 0.f, 0.f, 0.f};
  f32x4 o[4];
  float mrun[4], lrun[4];
#pragma unroll
  for (int g = 0; g < 4; g++) o[g] = zero;
#pragma unroll
  for (int r = 0; r < 4; r++) { mrun[r] = -1e30f; lrun[r] = 0.f; }

  auto stage = [&](int buf, int kb) {
    const u16* Kt = Kb + (size_t)kb * 64 * HD_;  // contiguous 64x64 tile
#pragma unroll
    for (int h = 0; h < 2; h++) {
      int c = h * 256 + wave * 64 + lane;
      int row = c >> 3, c8 = c & 7;
      int sw = c8 ^ (row & 7);
      gload_lds16(Kt + (size_t)((row << 3) | sw) * 8,
                  &Ks[buf][(size_t)(h * 256 + wave * 64) * 8]);
      gload_lds16(Vb + (size_t)row * T_ + kb * 64 + (sw << 3),
                  &Vs[buf][(size_t)(h * 256 + wave * 64) * 8]);
    }
  };

  stage(0, 0);
  for (int kb = 0; kb <= bx; ++kb) {
    int cur = kb & 1;
    __syncthreads();  // staged 'cur' landed (vmcnt0) across all waves
    if (kb < bx) stage(cur ^ 1, kb + 1);
    const u16* Ksb = Ks[cur];
    const u16* Vsb = Vs[cur];

    // --- QK^T (scores already in exp2 domain via pre-scaled Q) ---
    f32x4 s[4];
#pragma unroll
    for (int t = 0; t < 4; t++) s[t] = zero;
    __builtin_amdgcn_s_setprio(1);
#pragma unroll
    for (int t = 0; t < 4; t++) {
      int krow = t * 16 + laneM;
#pragma unroll
      for (int c = 0; c < 2; c++) {
        bf16x8 kf = *(const bf16x8*)(Ksb + krow * 64 +
                                     ((((c << 2) | laneQ) ^ (krow & 7)) << 3));
        s[t] = __builtin_amdgcn_mfma_f32_16x16x32_bf16(qf[c], kf, s[t], 0, 0, 0);
      }
    }
    __builtin_amdgcn_s_setprio(0);

    // causal mask (diagonal block only; off-diagonal needs nothing)
    if (kb == bx) {
#pragma unroll
      for (int t = 0; t < 4; t++)
#pragma unroll
        for (int r = 0; r < 4; r++) {
          int col = kb * 64 + t * 16 + laneM;
          int qrow = q0 + laneQ * 4 + r;
          if (col > qrow) s[t][r] = -1e30f;
        }
    }

    // --- lazy-max online softmax: no shuffles in steady state ---
    float lm[4];
#pragma unroll
    for (int r = 0; r < 4; r++)
      lm[r] = fmaxf(fmaxf(s[0][r], s[1][r]), fmaxf(s[2][r], s[3][r]));
    float dd = fmaxf(fmaxf(lm[0] - mrun[0], lm[1] - mrun[1]),
                     fmaxf(lm[2] - mrun[2], lm[3] - mrun[3]));
    if (__any(dd > DTHR)) {
#pragma unroll
      for (int r = 0; r < 4; r++) {
        float M = lm[r];
#pragma unroll
        for (int m = 1; m < 16; m <<= 1) M = fmaxf(M, __shfl_xor(M, m, 64));
        if (M > mrun[r]) {
          float sf = exp2f(mrun[r] - M);
          lrun[r] *= sf;
#pragma unroll
          for (int g = 0; g < 4; g++) o[g][r] *= sf;
          mrun[r] = M;
        }
      }
    }
    u16* pw = p_lds[wave];
#pragma unroll
    for (int r = 0; r < 4; r++) {
      float p0 = exp2f(s[0][r] - mrun[r]);
      float p1 = exp2f(s[1][r] - mrun[r]);
      float p2 = exp2f(s[2][r] - mrun[r]);
      float p3 = exp2f(s[3][r] - mrun[r]);
      lrun[r] += (p0 + p1) + (p2 + p3);   // per-lane partial; reduce at end
      int prow = laneQ * 4 + r;
      int sx = (prow & 7) << 3;          // XOR swizzle on 16B chunk
      u16* pr = pw + prow * 64;
      pr[laneM ^ sx]        = f2b(p0);
      pr[(16 + laneM) ^ sx] = f2b(p1);
      pr[(32 + laneM) ^ sx] = f2b(p2);
      pr[(48 + laneM) ^ sx] = f2b(p3);
    }
    asm volatile("s_waitcnt lgkmcnt(0)" ::: "memory");

    // --- PV: P[16x64] @ V[64x64] ---
    int swm = (laneM & 7) << 3;
    bf16x8 pf0 = *(const bf16x8*)(pw + laneM * 64 + ((laneQ << 3) ^ swm));
    bf16x8 pf1 = *(const bf16x8*)(pw + laneM * 64 + (((4 | laneQ) << 3) ^ swm));
    __builtin_amdgcn_s_setprio(1);
#pragma unroll
    for (int g = 0; g < 4; g++) {
      int d = g * 16 + laneM;
      bf16x8 v0 = *(const bf16x8*)(Vsb + d * 64 + ((laneQ ^ (d & 7)) << 3));
      bf16x8 v1 = *(const bf16x8*)(Vsb + d * 64 + (((4 | laneQ) ^ (d & 7)) << 3));
      o[g] = __builtin_amdgcn_mfma_f32_16x16x32_bf16(pf0, v0, o[g], 0, 0, 0);
      o[g] = __builtin_amdgcn_mfma_f32_16x16x32_bf16(pf1, v1, o[g], 0, 0, 0);
    }
    __builtin_amdgcn_s_setprio(0);
  }

  int b = bh / H_, h = bh % H_;
#pragma unroll
  for (int r = 0; r < 4; r++) {
    int t = q0 + laneQ * 4 + r;
    float l = lrun[r];
#pragma unroll
    for (int m = 1; m < 16; m <<= 1) l += __shfl_xor(l, m, 64);
    float inv = 1.0f / l;
    size_t base = ((size_t)(b * T_ + t)) * C_ + h * HD_;
#pragma unroll
    for (int g = 0; g < 4; g++)
      ctx[base + g * 16 + laneM] = f2b(o[g][r] * inv);
  }
}

// ---------------------------------------------------------------
extern "C" void kernel_launch(void* const* d_in, const int* in_sizes, int n_in,
                              void* d_out, int out_size, void* d_ws, size_t ws_size,
                              hipStream_t stream) {
  const float* x      = (const float*)d_in[0];
  const float* Wq     = (const float*)d_in[1];
  const float* Wk     = (const float*)d_in[2];
  const float* Wv     = (const float*)d_in[3];
  const float* Wo     = (const float*)d_in[4];
  const float* bo     = (const float*)d_in[5];
  const float* W_fc   = (const float*)d_in[6];
  const float* b_fc   = (const float*)d_in[7];
  const float* W_proj = (const float*)d_in[8];
  const float* b_proj = (const float*)d_in[9];
  const float* g1     = (const float*)d_in[10];
  const float* be1    = (const float*)d_in[11];
  const float* g2     = (const float*)d_in[12];
  const float* be2    = (const float*)d_in[13];
  float* out = (float*)d_out;

  char* ws = (char*)d_ws;
  size_t off = 0;
  auto alloc = [&](size_t bytes) {
    size_t o = off;
    off += (bytes + 255) & ~(size_t)255;
    return o;
  };
  u16*   xn    = (u16*)(ws + alloc((size_t)4096 * 768 * 2));
  u16*   xn2   = (u16*)(ws + alloc((size_t)4096 * 768 * 2));
  u16*   qkv   = (u16*)(ws + alloc((size_t)3 * 4096 * 768 * 2));
  u16*   ctx   = (u16*)(ws + alloc((size_t)4096 * 768 * 2));
  float* xa    = (float*)(ws + alloc((size_t)4096 * 768 * 4));
  u16*   hbuf  = (u16*)(ws + alloc((size_t)4096 * 3072 * 2));
  u16*   wqkvT = (u16*)(ws + alloc((size_t)2304 * 768 * 2));
  u16*   woT   = (u16*)(ws + alloc((size_t)768 * 768 * 2));
  u16*   wfcT  = (u16*)(ws + alloc((size_t)768 * 3072 * 2));
  u16*   wprT  = (u16*)(ws + alloc((size_t)3072 * 768 * 2));

  u16* q  = qkv;
  u16* k  = qkv + (size_t)4096 * 768;
  u16* vt = qkv + (size_t)2 * 4096 * 768;

  // LN1 + weight converts
  ln_kernel<<<4096, 256, 0, stream>>>(x, g1, be1, xn);
  tcvt4_kernel<<<dim3(24, 24, 4), 256, 0, stream>>>(
      Wq, Wk, Wv, Wo,
      wqkvT, wqkvT + (size_t)768 * 768, wqkvT + (size_t)2 * 768 * 768, woT);
  tcvt_kernel<<<dim3(96, 24), 256, 0, stream>>>(W_fc, wfcT, 768, 3072);
  tcvt_kernel<<<dim3(24, 96), 256, 0, stream>>>(W_proj, wprT, 3072, 768);

  // fused QKV projection: [4096,768] @ [768,2304]
  gemm_p<1><<<dim3(32, 36), 256, 0, stream>>>(xn, wqkvT, 768, 2304, qkv, nullptr, nullptr, nullptr);

  // causal flash attention -> ctx [B,T,C]
  attn_kernel<<<768, 256, 0, stream>>>(q, k, vt, ctx);

  // x_a = ctx @ Wo + bo + x   (fp32)
  gemm_p<3><<<dim3(32, 12), 256, 0, stream>>>(ctx, woT, 768, 768, nullptr, xa, bo, x);

  // LN2
  ln_kernel<<<4096, 256, 0, stream>>>(xa, g2, be2, xn2);

  // h = gelu(xn2 @ W_fc + b_fc)   (bf16)
  gemm_p<4><<<dim3(32, 48), 256, 0, stream>>>(xn2, wfcT, 768, 3072, hbuf, nullptr, b_fc, nullptr);

  // out = h @ W_proj + b_proj + x_a   (fp32)
  gemm_p<5><<<dim3(32, 12), 256, 0, stream>>>(hbuf, wprT, 3072, 768, nullptr, out, b_proj, xa);
}

// Round 8
// 203.607 us; speedup vs baseline: 1.0524x; 1.0524x over previous
//
#include <hip/hip_runtime.h>
#include <hip/hip_bf16.h>

#define B_  2
#define T_  2048
#define C_  768
#define H_  12
#define HD_ 64

// scores are computed in exp2 domain: Q is pre-scaled by 0.125*log2(e)
#define QSCALE 0.18033688011f
#define DTHR   11.5415603f   /* 8*log2(e) */

typedef short bf16x8 __attribute__((ext_vector_type(8)));
typedef float f32x4  __attribute__((ext_vector_type(4)));
typedef unsigned short u16;

__device__ __forceinline__ u16 f2b(float f) {
  __hip_bfloat16 h = __float2bfloat16(f);
  return __builtin_bit_cast(u16, h);
}

__device__ __forceinline__ void gload_lds16(const u16* g, u16* l) {
  __builtin_amdgcn_global_load_lds(
      (__attribute__((address_space(1))) void*)(void*)g,
      (__attribute__((address_space(3))) void*)(void*)l,
      16, 0, 0);
}

// ---------------- LayerNorm: fp32 in -> bf16 out ----------------
__global__ __launch_bounds__(256) void ln_kernel(const float* __restrict__ x,
                                                 const float* __restrict__ g,
                                                 const float* __restrict__ b,
                                                 u16* __restrict__ out) {
  int row = blockIdx.x;
  int tid = threadIdx.x;
  const float* xr = x + (size_t)row * C_;
  float v0 = xr[tid], v1 = xr[tid + 256], v2 = xr[tid + 512];
  float s = v0 + v1 + v2;
  float q = v0 * v0 + v1 * v1 + v2 * v2;
  for (int m = 1; m < 64; m <<= 1) {
    s += __shfl_xor(s, m, 64);
    q += __shfl_xor(q, m, 64);
  }
  __shared__ float red[8];
  int wv = tid >> 6, ln = tid & 63;
  if (ln == 0) { red[wv] = s; red[4 + wv] = q; }
  __syncthreads();
  s = red[0] + red[1] + red[2] + red[3];
  q = red[4] + red[5] + red[6] + red[7];
  float mu  = s * (1.0f / C_);
  float var = q * (1.0f / C_) - mu * mu;
  float rs  = rsqrtf(var + 1e-5f);
  u16* orow = out + (size_t)row * C_;
  orow[tid]       = f2b(g[tid]       * (v0 - mu) * rs + b[tid]);
  orow[tid + 256] = f2b(g[tid + 256] * (v1 - mu) * rs + b[tid + 256]);
  orow[tid + 512] = f2b(g[tid + 512] * (v2 - mu) * rs + b[tid + 512]);
}

// ------------- transpose+convert: fp32 W[K,N] -> bf16 Bt[N,K] -------------
__device__ __forceinline__ void tcvt_body(const float* __restrict__ W,
                                          u16* __restrict__ Bt,
                                          int Kd, int Nd, int bx, int by) {
  __shared__ u16 tile[32][33];
  int j0 = bx * 32, i0 = by * 32;
  int tx = threadIdx.x & 31, ty = threadIdx.x >> 5;  // ty 0..7
#pragma unroll
  for (int p = 0; p < 4; p++)
    tile[p * 8 + ty][tx] = f2b(W[(size_t)(i0 + p * 8 + ty) * Nd + j0 + tx]);
  __syncthreads();
#pragma unroll
  for (int p = 0; p < 4; p++)
    Bt[(size_t)(j0 + p * 8 + ty) * Kd + i0 + tx] = tile[tx][p * 8 + ty];
}

// all six weight transposes in ONE launch (flat 6912-block grid)
__global__ __launch_bounds__(256) void tcvt_all(const float* __restrict__ Wq,
                                                const float* __restrict__ Wk,
                                                const float* __restrict__ Wv,
                                                const float* __restrict__ Wo,
                                                const float* __restrict__ Wfc,
                                                const float* __restrict__ Wpr,
                                                u16* __restrict__ Oq,
                                                u16* __restrict__ Ok,
                                                u16* __restrict__ Ov,
                                                u16* __restrict__ Oo,
                                                u16* __restrict__ Ofc,
                                                u16* __restrict__ Opr) {
  int id = blockIdx.x;
  if (id < 2304) {                       // four 768x768, 576 tiles each
    int w = id / 576, idx = id - w * 576;
    const float* W = (w == 0) ? Wq : (w == 1) ? Wk : (w == 2) ? Wv : Wo;
    u16* O = (w == 0) ? Oq : (w == 1) ? Ok : (w == 2) ? Ov : Oo;
    tcvt_body(W, O, 768, 768, idx % 24, idx / 24);
  } else if (id < 4608) {                // W_fc [768,3072]
    int idx = id - 2304;
    tcvt_body(Wfc, Ofc, 768, 3072, idx % 96, idx / 96);
  } else {                               // W_proj [3072,768]
    int idx = id - 4608;
    tcvt_body(Wpr, Opr, 3072, 768, idx % 24, idx / 24);
  }
}

// ------------- GEMM: C[M,N] = A[M,K](bf16) * Bt[N,K]^T(bf16) -------------
// 128 x (NR*32) tile, BK=64, double-buffered LDS, ONE barrier per K-step
// (stage(t+1) issued right after the barrier; its vmcnt-drain happens at the
// NEXT barrier). XOR-swizzled LDS. NR=2: 48KB -> 3 blk/CU. NR=4: 64KB -> 2.
// MODE 1: fused QKV epilogue (q pre-scaled, [B,H,T,64]; k same; v^T [B,H,64,T])
// MODE 3/5: fp32 acc+bias+resid   4: bf16 gelu(acc+bias)
template <int MODE, int NR>
__global__ __launch_bounds__(256) void gemm_bt(const u16* __restrict__ A,
                                               const u16* __restrict__ Bt,
                                               int K, int N,
                                               u16* __restrict__ outB,
                                               float* __restrict__ outF,
                                               const float* __restrict__ bias,
                                               const float* __restrict__ resid) {
  constexpr int BN = NR * 32;
  __shared__ u16 As[2][128 * 64];
  __shared__ u16 Bs[2][BN * 64];
  int tid = threadIdx.x;
  int wave = tid >> 6, lane = tid & 63;
  int wr = wave >> 1, wc = wave & 1;
  int laneQ = lane >> 4, laneM = lane & 15;
  int bm = blockIdx.x * 128, bn = blockIdx.y * BN;

  f32x4 zero = {0.f, 0.f, 0.f, 0.f};
  f32x4 acc[4][NR];
#pragma unroll
  for (int m = 0; m < 4; m++)
#pragma unroll
    for (int n = 0; n < NR; n++) acc[m][n] = zero;

  auto stage = [&](int buf, int k0) {
#pragma unroll
    for (int i = 0; i < 4; i++) {
      int c = i * 256 + tid;
      int row = c >> 3, sw = (c & 7) ^ (row & 7);
      gload_lds16(A + (size_t)(bm + row) * K + k0 + (sw << 3),
                  &As[buf][(size_t)(i * 256 + wave * 64) * 8]);
    }
#pragma unroll
    for (int i = 0; i < NR; i++) {
      int c = i * 256 + tid;
      int row = c >> 3, sw = (c & 7) ^ (row & 7);
      gload_lds16(Bt + (size_t)(bn + row) * K + k0 + (sw << 3),
                  &Bs[buf][(size_t)(i * 256 + wave * 64) * 8]);
    }
  };

  auto compute = [&](int buf) {
    const u16* Ab = As[buf];
    const u16* Bb = Bs[buf];
#pragma unroll
    for (int kk = 0; kk < 2; kk++) {
      bf16x8 af[4], bfr[NR];
#pragma unroll
      for (int m = 0; m < 4; m++) {
        int row = wr * 64 + m * 16 + laneM;
        af[m] = *(const bf16x8*)(Ab + row * 64 +
                                 ((((kk << 2) | laneQ) ^ (row & 7)) << 3));
      }
#pragma unroll
      for (int n = 0; n < NR; n++) {
        int row = wc * (NR * 16) + n * 16 + laneM;
        bfr[n] = *(const bf16x8*)(Bb + row * 64 +
                                  ((((kk << 2) | laneQ) ^ (row & 7)) << 3));
      }
      __builtin_amdgcn_s_setprio(1);
#pragma unroll
      for (int m = 0; m < 4; m++)
#pragma unroll
        for (int n = 0; n < NR; n++)
          acc[m][n] = __builtin_amdgcn_mfma_f32_16x16x32_bf16(af[m], bfr[n],
                                                              acc[m][n], 0, 0, 0);
      __builtin_amdgcn_s_setprio(0);
    }
  };

  int nk = K >> 6;
  stage(0, 0);
  for (int t = 0; t < nk; ++t) {
    int cur = t & 1;
    __syncthreads();               // stage(t) landed in all waves
    if (t + 1 < nk) stage(cur ^ 1, (t + 1) << 6);
    compute(cur);
  }

  u16* kout  = outB + (size_t)4096 * 768;
  u16* vtout = outB + (size_t)2 * 4096 * 768;
#pragma unroll
  for (int m = 0; m < 4; m++) {
#pragma unroll
    for (int n = 0; n < NR; n++) {
#pragma unroll
      for (int r = 0; r < 4; r++) {
        int row = bm + wr * 64 + m * 16 + laneQ * 4 + r;
        int col = bn + wc * NR * 16 + n * 16 + laneM;
        float v = acc[m][n][r];
        if (MODE == 1) {
          int b = row >> 11, t = row & 2047;
          int which = col / 768;
          int cc = col - which * 768;
          int h = cc >> 6, d = cc & 63;
          if (which == 0)
            outB[(((size_t)(b * H_ + h)) * T_ + t) * HD_ + d] = f2b(v * QSCALE);
          else if (which == 1)
            kout[(((size_t)(b * H_ + h)) * T_ + t) * HD_ + d] = f2b(v);
          else
            vtout[(((size_t)(b * H_ + h)) * HD_ + d) * T_ + t] = f2b(v);
        } else if (MODE == 3 || MODE == 5) {
          outF[(size_t)row * N + col] = v + bias[col] + resid[(size_t)row * N + col];
        } else if (MODE == 4) {
          float u = v + bias[col];
          outB[(size_t)row * N + col] = f2b(0.5f * u * (1.0f + erff(u * 0.70710678118f)));
        }
      }
    }
  }
}

// ------------- flash attention, LDS-staged K/V, KVBLK=64 -------------
// Q (pre-scaled by 0.125*log2e), K: [B*H, T, 64] bf16. Vt: [B*H, 64, T] bf16.
// ctx out: [B, T, C] bf16. 4 waves x 16 q-rows; LDS exactly 40960B ->
// 4 blocks/CU. Snake-balanced 768-block LPT grid.
__global__ __launch_bounds__(256) void attn_kernel(const u16* __restrict__ Q,
                                                   const u16* __restrict__ K,
                                                   const u16* __restrict__ Vt,
                                                   u16* __restrict__ ctx) {
  __shared__ u16 Ks[2][4096];
  __shared__ u16 Vs[2][4096];
  __shared__ u16 p_lds[4][1024];   // [16 rows][64 cols], XOR-swizzled

  int tid = threadIdx.x;
  int wave = tid >> 6, lane = tid & 63;
  int laneQ = lane >> 4, laneM = lane & 15;
  int id = blockIdx.x;
  int pass = id >> 8, slot = id & 255;
  int ii = pass * 256 + ((pass == 1) ? 255 - slot : slot);  // snake balance
  int bh = ii % 24;
  int bx = 31 - ii / 24;   // LPT: longest first
  int q0 = bx * 64 + wave * 16;

  const u16* Qb = Q  + ((size_t)bh * T_ + q0) * HD_;
  const u16* Kb = K  + (size_t)bh * T_ * HD_;
  const u16* Vb = Vt + (size_t)bh * HD_ * T_;

  bf16x8 qf[2];
  qf[0] = *(const bf16x8*)(Qb + laneM * HD_ + laneQ * 8);
  qf[1] = *(const bf16x8*)(Qb + laneM * HD_ + 32 + laneQ * 8);

  f32x4 zero = {0.f, 0.f, 0.f, 0.f};
  f32x4 o[4];
  float mrun[4], lrun[4];
#pragma unroll
  for (int g = 0; g < 4; g++) o[g] = zero;
#pragma unroll
  for (int r = 0; r < 4; r++) { mrun[r] = -1e30f; lrun[r] = 0.f; }

  auto stage = [&](int buf, int kb) {
    const u16* Kt = Kb + (size_t)kb * 64 * HD_;  // contiguous 64x64 tile
#pragma unroll
    for (int h = 0; h < 2; h++) {
      int c = h * 256 + wave * 64 + lane;
      int row = c >> 3, c8 = c & 7;
      int sw = c8 ^ (row & 7);
      gload_lds16(Kt + (size_t)((row << 3) | sw) * 8,
                  &Ks[buf][(size_t)(h * 256 + wave * 64) * 8]);
      gload_lds16(Vb + (size_t)row * T_ + kb * 64 + (sw << 3),
                  &Vs[buf][(size_t)(h * 256 + wave * 64) * 8]);
    }
  };

  stage(0, 0);
  for (int kb = 0; kb <= bx; ++kb) {
    int cur = kb & 1;
    __syncthreads();  // staged 'cur' landed (vmcnt0) across all waves
    if (kb < bx) stage(cur ^ 1, kb + 1);
    const u16* Ksb = Ks[cur];
    const u16* Vsb = Vs[cur];

    // --- QK^T (scores already in exp2 domain via pre-scaled Q) ---
    f32x4 s[4];
#pragma unroll
    for (int t = 0; t < 4; t++) s[t] = zero;
    __builtin_amdgcn_s_setprio(1);
#pragma unroll
    for (int t = 0; t < 4; t++) {
      int krow = t * 16 + laneM;
#pragma unroll
      for (int c = 0; c < 2; c++) {
        bf16x8 kf = *(const bf16x8*)(Ksb + krow * 64 +
                                     ((((c << 2) | laneQ) ^ (krow & 7)) << 3));
        s[t] = __builtin_amdgcn_mfma_f32_16x16x32_bf16(qf[c], kf, s[t], 0, 0, 0);
      }
    }
    __builtin_amdgcn_s_setprio(0);

    // causal mask (diagonal block only; off-diagonal needs nothing)
    if (kb == bx) {
#pragma unroll
      for (int t = 0; t < 4; t++)
#pragma unroll
        for (int r = 0; r < 4; r++) {
          int col = kb * 64 + t * 16 + laneM;
          int qrow = q0 + laneQ * 4 + r;
          if (col > qrow) s[t][r] = -1e30f;
        }
    }

    // --- lazy-max online softmax: no shuffles in steady state ---
    float lm[4];
#pragma unroll
    for (int r = 0; r < 4; r++)
      lm[r] = fmaxf(fmaxf(s[0][r], s[1][r]), fmaxf(s[2][r], s[3][r]));
    float dd = fmaxf(fmaxf(lm[0] - mrun[0], lm[1] - mrun[1]),
                     fmaxf(lm[2] - mrun[2], lm[3] - mrun[3]));
    if (__any(dd > DTHR)) {
#pragma unroll
      for (int r = 0; r < 4; r++) {
        float M = lm[r];
#pragma unroll
        for (int m = 1; m < 16; m <<= 1) M = fmaxf(M, __shfl_xor(M, m, 64));
        if (M > mrun[r]) {
          float sf = exp2f(mrun[r] - M);
          lrun[r] *= sf;
#pragma unroll
          for (int g = 0; g < 4; g++) o[g][r] *= sf;
          mrun[r] = M;
        }
      }
    }
    u16* pw = p_lds[wave];
#pragma unroll
    for (int r = 0; r < 4; r++) {
      float p0 = exp2f(s[0][r] - mrun[r]);
      float p1 = exp2f(s[1][r] - mrun[r]);
      float p2 = exp2f(s[2][r] - mrun[r]);
      float p3 = exp2f(s[3][r] - mrun[r]);
      lrun[r] += (p0 + p1) + (p2 + p3);   // per-lane partial; reduce at end
      int prow = laneQ * 4 + r;
      int sx = (prow & 7) << 3;          // XOR swizzle on 16B chunk
      u16* pr = pw + prow * 64;
      pr[laneM ^ sx]        = f2b(p0);
      pr[(16 + laneM) ^ sx] = f2b(p1);
      pr[(32 + laneM) ^ sx] = f2b(p2);
      pr[(48 + laneM) ^ sx] = f2b(p3);
    }
    asm volatile("s_waitcnt lgkmcnt(0)" ::: "memory");

    // --- PV: P[16x64] @ V[64x64] ---
    int swm = (laneM & 7) << 3;
    bf16x8 pf0 = *(const bf16x8*)(pw + laneM * 64 + ((laneQ << 3) ^ swm));
    bf16x8 pf1 = *(const bf16x8*)(pw + laneM * 64 + (((4 | laneQ) << 3) ^ swm));
    __builtin_amdgcn_s_setprio(1);
#pragma unroll
    for (int g = 0; g < 4; g++) {
      int d = g * 16 + laneM;
      bf16x8 v0 = *(const bf16x8*)(Vsb + d * 64 + ((laneQ ^ (d & 7)) << 3));
      bf16x8 v1 = *(const bf16x8*)(Vsb + d * 64 + (((4 | laneQ) ^ (d & 7)) << 3));
      o[g] = __builtin_amdgcn_mfma_f32_16x16x32_bf16(pf0, v0, o[g], 0, 0, 0);
      o[g] = __builtin_amdgcn_mfma_f32_16x16x32_bf16(pf1, v1, o[g], 0, 0, 0);
    }
    __builtin_amdgcn_s_setprio(0);
  }

  int b = bh / H_, h = bh % H_;
#pragma unroll
  for (int r = 0; r < 4; r++) {
    int t = q0 + laneQ * 4 + r;
    float l = lrun[r];
#pragma unroll
    for (int m = 1; m < 16; m <<= 1) l += __shfl_xor(l, m, 64);
    float inv = 1.0f / l;
    size_t base = ((size_t)(b * T_ + t)) * C_ + h * HD_;
#pragma unroll
    for (int g = 0; g < 4; g++)
      ctx[base + g * 16 + laneM] = f2b(o[g][r] * inv);
  }
}

// ---------------------------------------------------------------
extern "C" void kernel_launch(void* const* d_in, const int* in_sizes, int n_in,
                              void* d_out, int out_size, void* d_ws, size_t ws_size,
                              hipStream_t stream) {
  const float* x      = (const float*)d_in[0];
  const float* Wq     = (const float*)d_in[1];
  const float* Wk     = (const float*)d_in[2];
  const float* Wv     = (const float*)d_in[3];
  const float* Wo     = (const float*)d_in[4];
  const float* bo     = (const float*)d_in[5];
  const float* W_fc   = (const float*)d_in[6];
  const float* b_fc   = (const float*)d_in[7];
  const float* W_proj = (const float*)d_in[8];
  const float* b_proj = (const float*)d_in[9];
  const float* g1     = (const float*)d_in[10];
  const float* be1    = (const float*)d_in[11];
  const float* g2     = (const float*)d_in[12];
  const float* be2    = (const float*)d_in[13];
  float* out = (float*)d_out;

  char* ws = (char*)d_ws;
  size_t off = 0;
  auto alloc = [&](size_t bytes) {
    size_t o = off;
    off += (bytes + 255) & ~(size_t)255;
    return o;
  };
  u16*   xn    = (u16*)(ws + alloc((size_t)4096 * 768 * 2));
  u16*   xn2   = (u16*)(ws + alloc((size_t)4096 * 768 * 2));
  u16*   qkv   = (u16*)(ws + alloc((size_t)3 * 4096 * 768 * 2));
  u16*   ctx   = (u16*)(ws + alloc((size_t)4096 * 768 * 2));
  float* xa    = (float*)(ws + alloc((size_t)4096 * 768 * 4));
  u16*   hbuf  = (u16*)(ws + alloc((size_t)4096 * 3072 * 2));
  u16*   wqkvT = (u16*)(ws + alloc((size_t)2304 * 768 * 2));
  u16*   woT   = (u16*)(ws + alloc((size_t)768 * 768 * 2));
  u16*   wfcT  = (u16*)(ws + alloc((size_t)768 * 3072 * 2));
  u16*   wprT  = (u16*)(ws + alloc((size_t)3072 * 768 * 2));

  u16* q  = qkv;
  u16* k  = qkv + (size_t)4096 * 768;
  u16* vt = qkv + (size_t)2 * 4096 * 768;

  // LN1 + all weight converts (one launch)
  ln_kernel<<<4096, 256, 0, stream>>>(x, g1, be1, xn);
  tcvt_all<<<6912, 256, 0, stream>>>(
      Wq, Wk, Wv, Wo, W_fc, W_proj,
      wqkvT, wqkvT + (size_t)768 * 768, wqkvT + (size_t)2 * 768 * 768,
      woT, wfcT, wprT);

  // fused QKV projection: [4096,768] @ [768,2304]  (128x128 dbuf)
  gemm_bt<1, 4><<<dim3(32, 18), 256, 0, stream>>>(xn, wqkvT, 768, 2304, qkv, nullptr, nullptr, nullptr);

  // causal flash attention -> ctx [B,T,C]
  attn_kernel<<<768, 256, 0, stream>>>(q, k, vt, ctx);

  // x_a = ctx @ Wo + bo + x   (fp32, 128x64 dbuf, 384 blocks)
  gemm_bt<3, 2><<<dim3(32, 12), 256, 0, stream>>>(ctx, woT, 768, 768, nullptr, xa, bo, x);

  // LN2
  ln_kernel<<<4096, 256, 0, stream>>>(xa, g2, be2, xn2);

  // h = gelu(xn2 @ W_fc + b_fc)   (bf16, 128x128 dbuf)
  gemm_bt<4, 4><<<dim3(32, 24), 256, 0, stream>>>(xn2, wfcT, 768, 3072, hbuf, nullptr, b_fc, nullptr);

  // out = h @ W_proj + b_proj + x_a   (fp32, 128x64 dbuf, 384 blocks)
  gemm_bt<5, 2><<<dim3(32, 12), 256, 0, stream>>>(hbuf, wprT, 3072, 768, nullptr, out, b_proj, xa);
}

// Round 9
// 189.973 us; speedup vs baseline: 1.1279x; 1.0718x over previous
//
#include <hip/hip_runtime.h>
#include <hip/hip_bf16.h>

#define B_  2
#define T_  2048
#define C_  768
#define H_  12
#define HD_ 64

// scores are computed in exp2 domain: Q is pre-scaled by 0.125*log2(e)
#define QSCALE 0.18033688011f
#define DTHR   11.5415603f   /* 8*log2(e) */

typedef short bf16x8 __attribute__((ext_vector_type(8)));
typedef float f32x4  __attribute__((ext_vector_type(4)));
typedef unsigned short u16;

__device__ __forceinline__ u16 f2b(float f) {
  __hip_bfloat16 h = __float2bfloat16(f);
  return __builtin_bit_cast(u16, h);
}

__device__ __forceinline__ void gload_lds16(const u16* g, u16* l) {
  __builtin_amdgcn_global_load_lds(
      (__attribute__((address_space(1))) void*)(void*)g,
      (__attribute__((address_space(3))) void*)(void*)l,
      16, 0, 0);
}

// ---------------- LayerNorm: fp32 in -> bf16 out ----------------
__global__ __launch_bounds__(256) void ln_kernel(const float* __restrict__ x,
                                                 const float* __restrict__ g,
                                                 const float* __restrict__ b,
                                                 u16* __restrict__ out) {
  int row = blockIdx.x;
  int tid = threadIdx.x;
  const float* xr = x + (size_t)row * C_;
  float v0 = xr[tid], v1 = xr[tid + 256], v2 = xr[tid + 512];
  float s = v0 + v1 + v2;
  float q = v0 * v0 + v1 * v1 + v2 * v2;
  for (int m = 1; m < 64; m <<= 1) {
    s += __shfl_xor(s, m, 64);
    q += __shfl_xor(q, m, 64);
  }
  __shared__ float red[8];
  int wv = tid >> 6, ln = tid & 63;
  if (ln == 0) { red[wv] = s; red[4 + wv] = q; }
  __syncthreads();
  s = red[0] + red[1] + red[2] + red[3];
  q = red[4] + red[5] + red[6] + red[7];
  float mu  = s * (1.0f / C_);
  float var = q * (1.0f / C_) - mu * mu;
  float rs  = rsqrtf(var + 1e-5f);
  u16* orow = out + (size_t)row * C_;
  orow[tid]       = f2b(g[tid]       * (v0 - mu) * rs + b[tid]);
  orow[tid + 256] = f2b(g[tid + 256] * (v1 - mu) * rs + b[tid + 256]);
  orow[tid + 512] = f2b(g[tid + 512] * (v2 - mu) * rs + b[tid + 512]);
}

// ------------- transpose+convert: fp32 W[K,N] -> bf16 Bt[N,K] -------------
__device__ __forceinline__ void tcvt_body(const float* __restrict__ W,
                                          u16* __restrict__ Bt,
                                          int Kd, int Nd, int bx, int by) {
  __shared__ u16 tile[32][33];
  int j0 = bx * 32, i0 = by * 32;
  int tx = threadIdx.x & 31, ty = threadIdx.x >> 5;  // ty 0..7
#pragma unroll
  for (int p = 0; p < 4; p++)
    tile[p * 8 + ty][tx] = f2b(W[(size_t)(i0 + p * 8 + ty) * Nd + j0 + tx]);
  __syncthreads();
#pragma unroll
  for (int p = 0; p < 4; p++)
    Bt[(size_t)(j0 + p * 8 + ty) * Kd + i0 + tx] = tile[tx][p * 8 + ty];
}

// all six weight transposes in ONE launch (flat 6912-block grid)
__global__ __launch_bounds__(256) void tcvt_all(const float* __restrict__ Wq,
                                                const float* __restrict__ Wk,
                                                const float* __restrict__ Wv,
                                                const float* __restrict__ Wo,
                                                const float* __restrict__ Wfc,
                                                const float* __restrict__ Wpr,
                                                u16* __restrict__ Oq,
                                                u16* __restrict__ Ok,
                                                u16* __restrict__ Ov,
                                                u16* __restrict__ Oo,
                                                u16* __restrict__ Ofc,
                                                u16* __restrict__ Opr) {
  int id = blockIdx.x;
  if (id < 2304) {                       // four 768x768, 576 tiles each
    int w = id / 576, idx = id - w * 576;
    const float* W = (w == 0) ? Wq : (w == 1) ? Wk : (w == 2) ? Wv : Wo;
    u16* O = (w == 0) ? Oq : (w == 1) ? Ok : (w == 2) ? Ov : Oo;
    tcvt_body(W, O, 768, 768, idx % 24, idx / 24);
  } else if (id < 4608) {                // W_fc [768,3072]
    int idx = id - 2304;
    tcvt_body(Wfc, Ofc, 768, 3072, idx % 96, idx / 96);
  } else {                               // W_proj [3072,768]
    int idx = id - 4608;
    tcvt_body(Wpr, Opr, 3072, 768, idx % 24, idx / 24);
  }
}

// ------------- GEMM: C[M,N] = A[M,K](bf16) * Bt[N,K]^T(bf16) -------------
// 128 x (NR*32) tile, template BK, double-buffered LDS, ONE barrier per
// K-step (stage(t+1) issued right after the barrier; drained at next one).
// XOR-swizzled LDS (inverse-swizzled global source, swizzled reads).
// <NR=4,BK=32>: 32KB -> 4 blk/CU, 16 MFMA/step.  <NR=2,BK=64>: 48KB -> 3.
// MODE 1: fused QKV epilogue (q pre-scaled, [B,H,T,64]; k same; v^T [B,H,64,T])
// MODE 3/5: fp32 acc+bias+resid   4: bf16 gelu(acc+bias)
template <int MODE, int NR, int BK>
__global__ __launch_bounds__(256) void gemm_bt(const u16* __restrict__ A,
                                               const u16* __restrict__ Bt,
                                               int K, int N,
                                               u16* __restrict__ outB,
                                               float* __restrict__ outF,
                                               const float* __restrict__ bias,
                                               const float* __restrict__ resid) {
  constexpr int BN = NR * 32;
  constexpr int CH = BK / 8;       // 16B chunks per row
  constexpr int KK = BK / 32;      // K slices per step
  __shared__ u16 As[2][128 * BK];
  __shared__ u16 Bs[2][BN * BK];
  int tid = threadIdx.x;
  int wave = tid >> 6, lane = tid & 63;
  int wr = wave >> 1, wc = wave & 1;
  int laneQ = lane >> 4, laneM = lane & 15;
  int bm = blockIdx.x * 128, bn = blockIdx.y * BN;

  f32x4 zero = {0.f, 0.f, 0.f, 0.f};
  f32x4 acc[4][NR];
#pragma unroll
  for (int m = 0; m < 4; m++)
#pragma unroll
    for (int n = 0; n < NR; n++) acc[m][n] = zero;

  auto stage = [&](int buf, int k0) {
#pragma unroll
    for (int i = 0; i < (128 * CH) / 256; i++) {
      int c = i * 256 + tid;
      int row = c / CH, sw = (c % CH) ^ (row & (CH - 1));
      gload_lds16(A + (size_t)(bm + row) * K + k0 + (sw << 3),
                  &As[buf][(size_t)(i * 256 + wave * 64) * 8]);
    }
#pragma unroll
    for (int i = 0; i < (BN * CH) / 256; i++) {
      int c = i * 256 + tid;
      int row = c / CH, sw = (c % CH) ^ (row & (CH - 1));
      gload_lds16(Bt + (size_t)(bn + row) * K + k0 + (sw << 3),
                  &Bs[buf][(size_t)(i * 256 + wave * 64) * 8]);
    }
  };

  auto compute = [&](int buf) {
    const u16* Ab = As[buf];
    const u16* Bb = Bs[buf];
#pragma unroll
    for (int kk = 0; kk < KK; kk++) {
      bf16x8 af[4], bfr[NR];
#pragma unroll
      for (int m = 0; m < 4; m++) {
        int row = wr * 64 + m * 16 + laneM;
        int ch = ((kk << 2) | laneQ) ^ (row & (CH - 1));
        af[m] = *(const bf16x8*)(Ab + row * BK + (ch << 3));
      }
#pragma unroll
      for (int n = 0; n < NR; n++) {
        int row = wc * (NR * 16) + n * 16 + laneM;
        int ch = ((kk << 2) | laneQ) ^ (row & (CH - 1));
        bfr[n] = *(const bf16x8*)(Bb + row * BK + (ch << 3));
      }
      __builtin_amdgcn_s_setprio(1);
#pragma unroll
      for (int m = 0; m < 4; m++)
#pragma unroll
        for (int n = 0; n < NR; n++)
          acc[m][n] = __builtin_amdgcn_mfma_f32_16x16x32_bf16(af[m], bfr[n],
                                                              acc[m][n], 0, 0, 0);
      __builtin_amdgcn_s_setprio(0);
    }
  };

  int nk = K / BK;
  stage(0, 0);
  for (int t = 0; t < nk; ++t) {
    int cur = t & 1;
    __syncthreads();               // stage(t) landed in all waves
    if (t + 1 < nk) stage(cur ^ 1, (t + 1) * BK);
    compute(cur);
  }

  u16* kout  = outB + (size_t)4096 * 768;
  u16* vtout = outB + (size_t)2 * 4096 * 768;
#pragma unroll
  for (int m = 0; m < 4; m++) {
#pragma unroll
    for (int n = 0; n < NR; n++) {
#pragma unroll
      for (int r = 0; r < 4; r++) {
        int row = bm + wr * 64 + m * 16 + laneQ * 4 + r;
        int col = bn + wc * NR * 16 + n * 16 + laneM;
        float v = acc[m][n][r];
        if (MODE == 1) {
          int b = row >> 11, t = row & 2047;
          int which = col / 768;
          int cc = col - which * 768;
          int h = cc >> 6, d = cc & 63;
          if (which == 0)
            outB[(((size_t)(b * H_ + h)) * T_ + t) * HD_ + d] = f2b(v * QSCALE);
          else if (which == 1)
            kout[(((size_t)(b * H_ + h)) * T_ + t) * HD_ + d] = f2b(v);
          else
            vtout[(((size_t)(b * H_ + h)) * HD_ + d) * T_ + t] = f2b(v);
        } else if (MODE == 3 || MODE == 5) {
          outF[(size_t)row * N + col] = v + bias[col] + resid[(size_t)row * N + col];
        } else if (MODE == 4) {
          float u = v + bias[col];
          outB[(size_t)row * N + col] = f2b(0.5f * u * (1.0f + erff(u * 0.70710678118f)));
        }
      }
    }
  }
}

// ------------- flash attention, LDS-staged K/V, KVBLK=64 -------------
// Q (pre-scaled by 0.125*log2e), K: [B*H, T, 64] bf16. Vt: [B*H, 64, T] bf16.
// ctx out: [B, T, C] bf16. 4 waves x 16 q-rows; LDS exactly 40960B ->
// 4 blocks/CU. Snake-balanced 768-block LPT grid.
__global__ __launch_bounds__(256) void attn_kernel(const u16* __restrict__ Q,
                                                   const u16* __restrict__ K,
                                                   const u16* __restrict__ Vt,
                                                   u16* __restrict__ ctx) {
  __shared__ u16 Ks[2][4096];
  __shared__ u16 Vs[2][4096];
  __shared__ u16 p_lds[4][1024];   // [16 rows][64 cols], XOR-swizzled

  int tid = threadIdx.x;
  int wave = tid >> 6, lane = tid & 63;
  int laneQ = lane >> 4, laneM = lane & 15;
  int id = blockIdx.x;
  int pass = id >> 8, slot = id & 255;
  int ii = pass * 256 + ((pass == 1) ? 255 - slot : slot);  // snake balance
  int bh = ii % 24;
  int bx = 31 - ii / 24;   // LPT: longest first
  int q0 = bx * 64 + wave * 16;

  const u16* Qb = Q  + ((size_t)bh * T_ + q0) * HD_;
  const u16* Kb = K  + (size_t)bh * T_ * HD_;
  const u16* Vb = Vt + (size_t)bh * HD_ * T_;

  bf16x8 qf[2];
  qf[0] = *(const bf16x8*)(Qb + laneM * HD_ + laneQ * 8);
  qf[1] = *(const bf16x8*)(Qb + laneM * HD_ + 32 + laneQ * 8);

  f32x4 zero = {0.f, 0.f, 0.f, 0.f};
  f32x4 o[4];
  float mrun[4], lrun[4];
#pragma unroll
  for (int g = 0; g < 4; g++) o[g] = zero;
#pragma unroll
  for (int r = 0; r < 4; r++) { mrun[r] = -1e30f; lrun[r] = 0.f; }

  auto stage = [&](int buf, int kb) {
    const u16* Kt = Kb + (size_t)kb * 64 * HD_;  // contiguous 64x64 tile
#pragma unroll
    for (int h = 0; h < 2; h++) {
      int c = h * 256 + wave * 64 + lane;
      int row = c >> 3, c8 = c & 7;
      int sw = c8 ^ (row & 7);
      gload_lds16(Kt + (size_t)((row << 3) | sw) * 8,
                  &Ks[buf][(size_t)(h * 256 + wave * 64) * 8]);
      gload_lds16(Vb + (size_t)row * T_ + kb * 64 + (sw << 3),
                  &Vs[buf][(size_t)(h * 256 + wave * 64) * 8]);
    }
  };

  stage(0, 0);
  for (int kb = 0; kb <= bx; ++kb) {
    int cur = kb & 1;
    __syncthreads();  // staged 'cur' landed (vmcnt0) across all waves
    if (kb < bx) stage(cur ^ 1, kb + 1);
    const u16* Ksb = Ks[cur];
    const u16* Vsb = Vs[cur];

    // --- QK^T (scores already in exp2 domain via pre-scaled Q) ---
    f32x4 s[4];
#pragma unroll
    for (int t = 0; t < 4; t++) s[t] = zero;
    __builtin_amdgcn_s_setprio(1);
#pragma unroll
    for (int t = 0; t < 4; t++) {
      int krow = t * 16 + laneM;
#pragma unroll
      for (int c = 0; c < 2; c++) {
        bf16x8 kf = *(const bf16x8*)(Ksb + krow * 64 +
                                     ((((c << 2) | laneQ) ^ (krow & 7)) << 3));
        s[t] = __builtin_amdgcn_mfma_f32_16x16x32_bf16(qf[c], kf, s[t], 0, 0, 0);
      }
    }
    __builtin_amdgcn_s_setprio(0);

    // causal mask (diagonal block only; off-diagonal needs nothing)
    if (kb == bx) {
#pragma unroll
      for (int t = 0; t < 4; t++)
#pragma unroll
        for (int r = 0; r < 4; r++) {
          int col = kb * 64 + t * 16 + laneM;
          int qrow = q0 + laneQ * 4 + r;
          if (col > qrow) s[t][r] = -1e30f;
        }
    }

    // --- lazy-max online softmax: no shuffles in steady state ---
    float lm[4];
#pragma unroll
    for (int r = 0; r < 4; r++)
      lm[r] = fmaxf(fmaxf(s[0][r], s[1][r]), fmaxf(s[2][r], s[3][r]));
    float dd = fmaxf(fmaxf(lm[0] - mrun[0], lm[1] - mrun[1]),
                     fmaxf(lm[2] - mrun[2], lm[3] - mrun[3]));
    if (__any(dd > DTHR)) {
#pragma unroll
      for (int r = 0; r < 4; r++) {
        float M = lm[r];
#pragma unroll
        for (int m = 1; m < 16; m <<= 1) M = fmaxf(M, __shfl_xor(M, m, 64));
        if (M > mrun[r]) {
          float sf = exp2f(mrun[r] - M);
          lrun[r] *= sf;
#pragma unroll
          for (int g = 0; g < 4; g++) o[g][r] *= sf;
          mrun[r] = M;
        }
      }
    }
    u16* pw = p_lds[wave];
#pragma unroll
    for (int r = 0; r < 4; r++) {
      float p0 = exp2f(s[0][r] - mrun[r]);
      float p1 = exp2f(s[1][r] - mrun[r]);
      float p2 = exp2f(s[2][r] - mrun[r]);
      float p3 = exp2f(s[3][r] - mrun[r]);
      lrun[r] += (p0 + p1) + (p2 + p3);   // per-lane partial; reduce at end
      int prow = laneQ * 4 + r;
      int sx = (prow & 7) << 3;          // XOR swizzle on 16B chunk
      u16* pr = pw + prow * 64;
      pr[laneM ^ sx]        = f2b(p0);
      pr[(16 + laneM) ^ sx] = f2b(p1);
      pr[(32 + laneM) ^ sx] = f2b(p2);
      pr[(48 + laneM) ^ sx] = f2b(p3);
    }
    asm volatile("s_waitcnt lgkmcnt(0)" ::: "memory");

    // --- PV: P[16x64] @ V[64x64] ---
    int swm = (laneM & 7) << 3;
    bf16x8 pf0 = *(const bf16x8*)(pw + laneM * 64 + ((laneQ << 3) ^ swm));
    bf16x8 pf1 = *(const bf16x8*)(pw + laneM * 64 + (((4 | laneQ) << 3) ^ swm));
    __builtin_amdgcn_s_setprio(1);
#pragma unroll
    for (int g = 0; g < 4; g++) {
      int d = g * 16 + laneM;
      bf16x8 v0 = *(const bf16x8*)(Vsb + d * 64 + ((laneQ ^ (d & 7)) << 3));
      bf16x8 v1 = *(const bf16x8*)(Vsb + d * 64 + (((4 | laneQ) ^ (d & 7)) << 3));
      o[g] = __builtin_amdgcn_mfma_f32_16x16x32_bf16(pf0, v0, o[g], 0, 0, 0);
      o[g] = __builtin_amdgcn_mfma_f32_16x16x32_bf16(pf1, v1, o[g], 0, 0, 0);
    }
    __builtin_amdgcn_s_setprio(0);
  }

  int b = bh / H_, h = bh % H_;
#pragma unroll
  for (int r = 0; r < 4; r++) {
    int t = q0 + laneQ * 4 + r;
    float l = lrun[r];
#pragma unroll
    for (int m = 1; m < 16; m <<= 1) l += __shfl_xor(l, m, 64);
    float inv = 1.0f / l;
    size_t base = ((size_t)(b * T_ + t)) * C_ + h * HD_;
#pragma unroll
    for (int g = 0; g < 4; g++)
      ctx[base + g * 16 + laneM] = f2b(o[g][r] * inv);
  }
}

// ---------------------------------------------------------------
extern "C" void kernel_launch(void* const* d_in, const int* in_sizes, int n_in,
                              void* d_out, int out_size, void* d_ws, size_t ws_size,
                              hipStream_t stream) {
  const float* x      = (const float*)d_in[0];
  const float* Wq     = (const float*)d_in[1];
  const float* Wk     = (const float*)d_in[2];
  const float* Wv     = (const float*)d_in[3];
  const float* Wo     = (const float*)d_in[4];
  const float* bo     = (const float*)d_in[5];
  const float* W_fc   = (const float*)d_in[6];
  const float* b_fc   = (const float*)d_in[7];
  const float* W_proj = (const float*)d_in[8];
  const float* b_proj = (const float*)d_in[9];
  const float* g1     = (const float*)d_in[10];
  const float* be1    = (const float*)d_in[11];
  const float* g2     = (const float*)d_in[12];
  const float* be2    = (const float*)d_in[13];
  float* out = (float*)d_out;

  char* ws = (char*)d_ws;
  size_t off = 0;
  auto alloc = [&](size_t bytes) {
    size_t o = off;
    off += (bytes + 255) & ~(size_t)255;
    return o;
  };
  u16*   xn    = (u16*)(ws + alloc((size_t)4096 * 768 * 2));
  u16*   xn2   = (u16*)(ws + alloc((size_t)4096 * 768 * 2));
  u16*   qkv   = (u16*)(ws + alloc((size_t)3 * 4096 * 768 * 2));
  u16*   ctx   = (u16*)(ws + alloc((size_t)4096 * 768 * 2));
  float* xa    = (float*)(ws + alloc((size_t)4096 * 768 * 4));
  u16*   hbuf  = (u16*)(ws + alloc((size_t)4096 * 3072 * 2));
  u16*   wqkvT = (u16*)(ws + alloc((size_t)2304 * 768 * 2));
  u16*   woT   = (u16*)(ws + alloc((size_t)768 * 768 * 2));
  u16*   wfcT  = (u16*)(ws + alloc((size_t)768 * 3072 * 2));
  u16*   wprT  = (u16*)(ws + alloc((size_t)3072 * 768 * 2));

  u16* q  = qkv;
  u16* k  = qkv + (size_t)4096 * 768;
  u16* vt = qkv + (size_t)2 * 4096 * 768;

  // LN1 + all weight converts (one launch)
  ln_kernel<<<4096, 256, 0, stream>>>(x, g1, be1, xn);
  tcvt_all<<<6912, 256, 0, stream>>>(
      Wq, Wk, Wv, Wo, W_fc, W_proj,
      wqkvT, wqkvT + (size_t)768 * 768, wqkvT + (size_t)2 * 768 * 768,
      woT, wfcT, wprT);

  // fused QKV projection: [4096,768] @ [768,2304]  (128x128, BK32, 4 blk/CU)
  gemm_bt<1, 4, 32><<<dim3(32, 18), 256, 0, stream>>>(xn, wqkvT, 768, 2304, qkv, nullptr, nullptr, nullptr);

  // causal flash attention -> ctx [B,T,C]
  attn_kernel<<<768, 256, 0, stream>>>(q, k, vt, ctx);

  // x_a = ctx @ Wo + bo + x   (fp32, 128x64 BK64 dbuf, 384 blocks)
  gemm_bt<3, 2, 64><<<dim3(32, 12), 256, 0, stream>>>(ctx, woT, 768, 768, nullptr, xa, bo, x);

  // LN2
  ln_kernel<<<4096, 256, 0, stream>>>(xa, g2, be2, xn2);

  // h = gelu(xn2 @ W_fc + b_fc)   (bf16, 128x128 BK32)
  gemm_bt<4, 4, 32><<<dim3(32, 24), 256, 0, stream>>>(xn2, wfcT, 768, 3072, hbuf, nullptr, b_fc, nullptr);

  // out = h @ W_proj + b_proj + x_a   (fp32, 128x64 BK64 dbuf, 384 blocks)
  gemm_bt<5, 2, 64><<<dim3(32, 12), 256, 0, stream>>>(hbuf, wprT, 3072, 768, nullptr, out, b_proj, xa);
}